// Round 19
// baseline (38.649 us; speedup 1.0000x reference)
//
#include <hip/hip_runtime.h>

// Bidirectional Chamfer loss — R19 MEASUREMENT ROUND (prologue cost).
// Base = R14 (best, 24.19us) with ONLY the query-load+precompute block
// wrapped in an idempotent REP_P=8 loop (opaque base vs CSE; asm sinks
// keep each rep's loads live vs DCE — rule 17). Same addresses each rep,
// last rep feeds the scan -> bit-identical output.
// dur = 24.19 + 7 * P_load. Decision: small delta -> P is stores/launch,
// attack those or declare floor; large delta -> coalesce query delivery.

#define QPT    16     // query points per thread
#define BIGF   3.4e38f
#define REP_P  8      // prologue repeats

// ws layout (floats):
//  dir1 partials [b][ch][q] : 4 x 32 x 8192 = 1,048,576
//  dir2 partials [b][ch][q] : 4 x 128 x 2048 = 1,048,576 (at P2_OFF)
//  psum: RBLOCKS floats at PSUM_OFF
#define P2_OFF   1048576
#define PSUM_OFF 2097152
#define RBLOCKS  640

__global__ __launch_bounds__(256) void chamfer_kernel(
    const float* __restrict__ shape,  // [4, 8192, 3]
    const float* __restrict__ skel,   // [4, 2048, 3]
    float* __restrict__ pw)           // partial mins
{
    const int b   = blockIdx.y;
    const int tid = threadIdx.x;

    const float* q; float* pbase; const float* ssrc;
    int q0, qstride, lbase, scount;
    int x = blockIdx.x;
    if (x < 64) {                     // dir1: shape -> skel
        const int qb = x >> 5, ch = x & 31;
        pbase   = pw + ((size_t)b * 32 + ch) * 8192;
        q0      = qb * 4096 + tid;    // queries q0 + k*256, k<16
        qstride = 256;
        lbase   = 0;  scount = 64;
        ssrc    = skel + ((size_t)b * 2048 + ch * 64) * 3;
        q       = shape + (size_t)b * 8192 * 3;
    } else {                          // dir2: skel -> shape
        const int z = x - 64, half = tid >> 7;
        const int ch = 2 * z + half;
        pbase   = pw + P2_OFF + ((size_t)b * 128 + ch) * 2048;
        q0      = tid & 127;          // queries q0 + k*128, k<16
        qstride = 128;
        lbase   = half * 64;  scount = 128;
        ssrc    = shape + ((size_t)b * 8192 + z * 128) * 3;
        q       = skel + (size_t)b * 2048 * 3;
    }

    __shared__ float4 lds[128];

    // Stage targets as (x, y, z, |t|^2). dir1: 64, dir2: 128 (two chunks).
    if (tid < scount) {
        float tx = ssrc[tid * 3 + 0], ty = ssrc[tid * 3 + 1], tz = ssrc[tid * 3 + 2];
        lds[tid] = make_float4(tx, ty, tz, tx * tx + ty * ty + tz * tz);
    }

    // PROLOGUE under measurement: load my QPT query points + precompute,
    // repeated REP_P times (idempotent: same addresses, same values).
    const int qs3 = qstride * 3;
    float nqx[QPT], nqy[QPT], nqz[QPT], qsq[QPT], mn[QPT];
    #pragma unroll
    for (int k = 0; k < QPT; ++k) mn[k] = BIGF;

    int ib = 0;                                   // opaque base vs CSE
    #pragma unroll 1
    for (int rep = 0; rep < REP_P; ++rep) {
        asm volatile("" : "+v"(ib));
        const float* qp = q + (size_t)(q0 + ib) * 3;
        #pragma unroll
        for (int k = 0; k < QPT; ++k) {
            float xq = qp[k * qs3 + 0];
            float yq = qp[k * qs3 + 1];
            float zq = qp[k * qs3 + 2];
            nqx[k] = -2.0f * xq; nqy[k] = -2.0f * yq; nqz[k] = -2.0f * zq;
            qsq[k] = xq * xq + yq * yq + zq * zq;
            // keep this rep's results live (defeat dead-load elimination)
            asm volatile("" :: "v"(nqx[k]), "v"(nqy[k]),
                              "v"(nqz[k]), "v"(qsq[k]));
        }
    }

    __syncthreads();

    // Scan 64 targets (R14-identical): per 2 targets & query ->
    // 6 FMA + 1 v_min3_f32.
    #pragma unroll 2
    for (int j = 0; j < 64; j += 2) {
        float4 ta = lds[lbase + j + 0];           // broadcast: conflict-free
        float4 tb = lds[lbase + j + 1];
        #pragma unroll
        for (int k = 0; k < QPT; ++k) {
            float e0 = fmaf(nqx[k], ta.x,
                       fmaf(nqy[k], ta.y, fmaf(nqz[k], ta.z, ta.w)));
            float e1 = fmaf(nqx[k], tb.x,
                       fmaf(nqy[k], tb.y, fmaf(nqz[k], tb.z, tb.w)));
            mn[k] = fminf(fminf(mn[k], e0), e1);  // v_min3_f32
        }
    }

    // One coalesced store per (query, chunk) partial — no atomics.
    #pragma unroll
    for (int k = 0; k < QPT; ++k)
        pbase[q0 + k * qstride] = qsq[k] + mn[k];
}

// 640 blocks: 64 queries/block, 4 lanes per query split over chunks.
// Blocks 0..511 = dir1 (32 chunks), 512..639 = dir2 (128 chunks).
__global__ __launch_bounds__(256) void reduce_kernel(
    const float* __restrict__ pw, float* __restrict__ psum)
{
    const int blk = blockIdx.x, tid = threadIdx.x;
    const int sub = tid & 3, qi = tid >> 2;       // 4 lanes per query

    float m = BIGF;
    if (blk < 512) {                              // dir1: 8 loads/lane
        const int b  = blk >> 7;
        const int ql = ((blk & 127) << 6) + qi;
        const float* p = pw + (size_t)b * 32 * 8192 + ql;
        #pragma unroll
        for (int i = 0; i < 8; ++i)
            m = fminf(m, p[(sub * 8 + i) * 8192]);
    } else {                                      // dir2: 32 loads/lane
        const int z  = blk - 512;
        const int b  = z >> 5;
        const int ql = ((z & 31) << 6) + qi;
        const float* p = pw + P2_OFF + (size_t)b * 128 * 2048 + ql;
        #pragma unroll
        for (int i = 0; i < 32; ++i)
            m = fminf(m, p[(sub * 32 + i) * 2048]);
    }

    // Min across the 4-lane group, clamp, keep one copy.
    m = fminf(m, __shfl_xor(m, 1));
    m = fminf(m, __shfl_xor(m, 2));
    float s = (sub == 0) ? fmaxf(m, 0.0f) : 0.0f;

    // Wave + block sum.
    #pragma unroll
    for (int off = 32; off > 0; off >>= 1)
        s += __shfl_down(s, off);

    __shared__ float wsum[4];
    const int lane = tid & 63, w = tid >> 6;
    if (lane == 0) wsum[w] = s;
    __syncthreads();
    if (tid == 0) psum[blk] = (wsum[0] + wsum[1]) + (wsum[2] + wsum[3]);
}

__global__ __launch_bounds__(256) void final_kernel(
    const float* __restrict__ psum, float* __restrict__ out)
{
    float s = psum[threadIdx.x] + psum[threadIdx.x + 256];
    if (threadIdx.x < 128) s += psum[threadIdx.x + 512];

    #pragma unroll
    for (int off = 32; off > 0; off >>= 1)
        s += __shfl_down(s, off);

    __shared__ float wsum[4];
    const int lane = threadIdx.x & 63, w = threadIdx.x >> 6;
    if (lane == 0) wsum[w] = s;
    __syncthreads();
    if (threadIdx.x == 0)
        out[0] = ((wsum[0] + wsum[1]) + (wsum[2] + wsum[3])) * 1.0e-4f;
}

extern "C" void kernel_launch(void* const* d_in, const int* in_sizes, int n_in,
                              void* d_out, int out_size, void* d_ws, size_t ws_size,
                              hipStream_t stream) {
    const float* shape = (const float*)d_in[0];   // [4, 8192, 3]
    const float* skel  = (const float*)d_in[1];   // [4, 2048, 3]
    float* out         = (float*)d_out;           // scalar f32
    float* pw          = (float*)d_ws;

    // 128 tiles/batch x 4 batches = 512 blocks (2/CU, 8 waves/CU).
    chamfer_kernel<<<dim3(128, 4), 256, 0, stream>>>(shape, skel, pw);

    // 640 blocks, then tiny deterministic final sum.
    reduce_kernel<<<RBLOCKS, 256, 0, stream>>>(pw, pw + PSUM_OFF);
    final_kernel<<<1, 256, 0, stream>>>(pw + PSUM_OFF, out);
}

// Round 20
// 27.244 us; speedup vs baseline: 1.4186x; 1.4186x over previous
//
#include <hip/hip_runtime.h>

// Bidirectional Chamfer loss, fused:
//   out = 1e-4 * ( sum_n min_m |shape[b,n]-skel[b,m]|^2
//                + sum_m min_n |skel[b,m]-shape[b,n]|^2 )
//
// R20: budget after R11/R19 measurements: scan 9.7us, prologue 2.1,
// reduce 0.6, final 0.2, ~10 structural. HW-model fix: MI355X's 157 TF
// FP32 needs PACKED v_pk_fma_f32 (scalar v_fma = 79-103 TF, m07). Scan
// repacked: LDS holds target PAIRS as SoA f32x2 {(ax,bx),(ay,by),(az,bz),
// (asq,bsq)}; queries duplicated to (nq,nq) pairs; per 2 targets & query:
// 3 v_pk_fma_f32 + 1 v_min3_f32 (was 7 scalar ops). Same FMA order ->
// bit-identical. Base = R14 (best 24.19); reduce/final verbatim.

#define QPT    16     // query points per thread
#define BIGF   3.4e38f

typedef float f32x2 __attribute__((ext_vector_type(2)));

// ws layout (floats):
//  dir1 partials [b][ch][q] : 4 x 32 x 8192 = 1,048,576
//  dir2 partials [b][ch][q] : 4 x 128 x 2048 = 1,048,576 (at P2_OFF)
//  psum: RBLOCKS floats at PSUM_OFF
#define P2_OFF   1048576
#define PSUM_OFF 2097152
#define RBLOCKS  640

__global__ __launch_bounds__(256) void chamfer_kernel(
    const float* __restrict__ shape,  // [4, 8192, 3]
    const float* __restrict__ skel,   // [4, 2048, 3]
    float* __restrict__ pw)           // partial mins
{
    const int b   = blockIdx.y;
    const int tid = threadIdx.x;

    const float* q; float* pbase; const float* ssrc;
    int q0, qstride, lbase2, scount;
    int x = blockIdx.x;
    if (x < 64) {                     // dir1: shape -> skel
        const int qb = x >> 5, ch = x & 31;
        pbase   = pw + ((size_t)b * 32 + ch) * 8192;
        q0      = qb * 4096 + tid;    // queries q0 + k*256, k<16
        qstride = 256;
        lbase2  = 0;  scount = 64;
        ssrc    = skel + ((size_t)b * 2048 + ch * 64) * 3;
        q       = shape + (size_t)b * 8192 * 3;
    } else {                          // dir2: skel -> shape
        const int z = x - 64, half = tid >> 7;
        const int ch = 2 * z + half;
        pbase   = pw + P2_OFF + ((size_t)b * 128 + ch) * 2048;
        q0      = tid & 127;          // queries q0 + k*128, k<16
        qstride = 128;
        lbase2  = half * 32;  scount = 128;
        ssrc    = shape + ((size_t)b * 8192 + z * 128) * 3;
        q       = skel + (size_t)b * 2048 * 3;
    }

    // LDS: 64 target-pairs x 4 components, each an f32x2 (lane0=target a,
    // lane1=target b of the pair). Flattened: [(pair*4 + comp)] .
    __shared__ f32x2 lds2[256];

    // Stage: thread t computes target t's (x,y,z,|t|^2) and scatters the
    // 4 floats into component slot (t&1) of pair (t>>1).
    if (tid < scount) {
        float tx = ssrc[tid * 3 + 0], ty = ssrc[tid * 3 + 1], tz = ssrc[tid * 3 + 2];
        float tw = fmaf(tx, tx, fmaf(ty, ty, tz * tz));
        // dir2: thread tid stages block-target tid; its pair index already
        // includes the half offset because tid spans 0..127.
        const int pr = tid >> 1, c = tid & 1;
        float* lf = (float*)lds2;
        lf[(pr * 4 + 0) * 2 + c] = tx;
        lf[(pr * 4 + 1) * 2 + c] = ty;
        lf[(pr * 4 + 2) * 2 + c] = tz;
        lf[(pr * 4 + 3) * 2 + c] = tw;
    }

    // My QPT query points: precompute duplicated (-2q,-2q) pairs + |q|^2.
    const float* qp = q + (size_t)q0 * 3;
    const int qs3 = qstride * 3;
    f32x2 nqx[QPT], nqy[QPT], nqz[QPT];
    float qsq[QPT], mn[QPT];
    #pragma unroll
    for (int k = 0; k < QPT; ++k) {
        float xq = qp[k * qs3 + 0];
        float yq = qp[k * qs3 + 1];
        float zq = qp[k * qs3 + 2];
        float nx = -2.0f * xq, ny = -2.0f * yq, nz = -2.0f * zq;
        nqx[k][0] = nx; nqx[k][1] = nx;
        nqy[k][0] = ny; nqy[k][1] = ny;
        nqz[k][0] = nz; nqz[k][1] = nz;
        qsq[k] = xq * xq + yq * yq + zq * zq;
        mn[k]  = BIGF;
    }

    __syncthreads();

    // Scan 32 target-pairs: per pair & query -> 3 v_pk_fma_f32 + 1 min3.
    // FMA order matches the scalar version (z -> y -> x, seeded by tsq).
    #pragma unroll 4
    for (int j = 0; j < 32; ++j) {
        const int p4 = (lbase2 + j) * 4;
        f32x2 TX = lds2[p4 + 0];                  // broadcast: conflict-free
        f32x2 TY = lds2[p4 + 1];
        f32x2 TZ = lds2[p4 + 2];
        f32x2 TS = lds2[p4 + 3];
        #pragma unroll
        for (int k = 0; k < QPT; ++k) {
            f32x2 acc = TS;
            asm("v_pk_fma_f32 %0, %1, %2, %0" : "+v"(acc) : "v"(nqz[k]), "v"(TZ));
            asm("v_pk_fma_f32 %0, %1, %2, %0" : "+v"(acc) : "v"(nqy[k]), "v"(TY));
            asm("v_pk_fma_f32 %0, %1, %2, %0" : "+v"(acc) : "v"(nqx[k]), "v"(TX));
            mn[k] = fminf(fminf(mn[k], acc[0]), acc[1]);   // v_min3_f32
        }
    }

    // One coalesced store per (query, chunk) partial — no atomics.
    #pragma unroll
    for (int k = 0; k < QPT; ++k)
        pbase[q0 + k * qstride] = qsq[k] + mn[k];
}

// 640 blocks: 64 queries/block, 4 lanes per query split over chunks.
// Blocks 0..511 = dir1 (32 chunks), 512..639 = dir2 (128 chunks).
__global__ __launch_bounds__(256) void reduce_kernel(
    const float* __restrict__ pw, float* __restrict__ psum)
{
    const int blk = blockIdx.x, tid = threadIdx.x;
    const int sub = tid & 3, qi = tid >> 2;       // 4 lanes per query

    float m = BIGF;
    if (blk < 512) {                              // dir1: 8 loads/lane
        const int b  = blk >> 7;
        const int ql = ((blk & 127) << 6) + qi;
        const float* p = pw + (size_t)b * 32 * 8192 + ql;
        #pragma unroll
        for (int i = 0; i < 8; ++i)
            m = fminf(m, p[(sub * 8 + i) * 8192]);
    } else {                                      // dir2: 32 loads/lane
        const int z  = blk - 512;
        const int b  = z >> 5;
        const int ql = ((z & 31) << 6) + qi;
        const float* p = pw + P2_OFF + (size_t)b * 128 * 2048 + ql;
        #pragma unroll
        for (int i = 0; i < 32; ++i)
            m = fminf(m, p[(sub * 32 + i) * 2048]);
    }

    // Min across the 4-lane group, clamp, keep one copy.
    m = fminf(m, __shfl_xor(m, 1));
    m = fminf(m, __shfl_xor(m, 2));
    float s = (sub == 0) ? fmaxf(m, 0.0f) : 0.0f;

    // Wave + block sum.
    #pragma unroll
    for (int off = 32; off > 0; off >>= 1)
        s += __shfl_down(s, off);

    __shared__ float wsum[4];
    const int lane = tid & 63, w = tid >> 6;
    if (lane == 0) wsum[w] = s;
    __syncthreads();
    if (tid == 0) psum[blk] = (wsum[0] + wsum[1]) + (wsum[2] + wsum[3]);
}

__global__ __launch_bounds__(256) void final_kernel(
    const float* __restrict__ psum, float* __restrict__ out)
{
    float s = psum[threadIdx.x] + psum[threadIdx.x + 256];
    if (threadIdx.x < 128) s += psum[threadIdx.x + 512];

    #pragma unroll
    for (int off = 32; off > 0; off >>= 1)
        s += __shfl_down(s, off);

    __shared__ float wsum[4];
    const int lane = threadIdx.x & 63, w = threadIdx.x >> 6;
    if (lane == 0) wsum[w] = s;
    __syncthreads();
    if (threadIdx.x == 0)
        out[0] = ((wsum[0] + wsum[1]) + (wsum[2] + wsum[3])) * 1.0e-4f;
}

extern "C" void kernel_launch(void* const* d_in, const int* in_sizes, int n_in,
                              void* d_out, int out_size, void* d_ws, size_t ws_size,
                              hipStream_t stream) {
    const float* shape = (const float*)d_in[0];   // [4, 8192, 3]
    const float* skel  = (const float*)d_in[1];   // [4, 2048, 3]
    float* out         = (float*)d_out;           // scalar f32
    float* pw          = (float*)d_ws;

    // 128 tiles/batch x 4 batches = 512 blocks (2/CU, 8 waves/CU).
    chamfer_kernel<<<dim3(128, 4), 256, 0, stream>>>(shape, skel, pw);

    // 640 blocks, then tiny deterministic final sum.
    reduce_kernel<<<RBLOCKS, 256, 0, stream>>>(pw, pw + PSUM_OFF);
    final_kernel<<<1, 256, 0, stream>>>(pw + PSUM_OFF, out);
}

// Round 21
// 24.420 us; speedup vs baseline: 1.5827x; 1.1157x over previous
//
#include <hip/hip_runtime.h>

// Bidirectional Chamfer loss, fused:
//   out = 1e-4 * ( sum_n min_m |shape[b,n]-skel[b,m]|^2
//                + sum_m min_n |skel[b,m]-shape[b,n]|^2 )
//
// R21: FINAL — revert to R14 exactly (best measured: 24.19us).
// Session evidence: scan 9.7us (VALU-issue saturated), prologue 2.1,
// reduce 0.6, final 0.2, ~10-11us fixed 3-dispatch graph overhead.
// Ten structural variants of the scan/delivery (LDS/VMEM/SMEM/DPP/
// desync/pipeline/QPT-grid/pk_fma/fusion x2) all landed 24.2-29.8.
//
// Structure: QPT=16 query points per thread (strided), 64-target LDS
// chunks as (x,y,z,|t|^2), inner loop = 6 FMA + 1 v_min3_f32 per
// 2 targets & query; per-(query,chunk) partial mins to workspace
// (written exactly once, no atomics); 640-block min+clamp+sum reduce;
// 1-block deterministic final sum.

#define QPT    16     // query points per thread
#define BIGF   3.4e38f

// ws layout (floats):
//  dir1 partials [b][ch][q] : 4 x 32 x 8192 = 1,048,576
//  dir2 partials [b][ch][q] : 4 x 128 x 2048 = 1,048,576 (at P2_OFF)
//  psum: RBLOCKS floats at PSUM_OFF
#define P2_OFF   1048576
#define PSUM_OFF 2097152
#define RBLOCKS  640

__global__ __launch_bounds__(256) void chamfer_kernel(
    const float* __restrict__ shape,  // [4, 8192, 3]
    const float* __restrict__ skel,   // [4, 2048, 3]
    float* __restrict__ pw)           // partial mins
{
    const int b   = blockIdx.y;
    const int tid = threadIdx.x;

    const float* q; float* pbase; const float* ssrc;
    int q0, qstride, lbase, scount;
    int x = blockIdx.x;
    if (x < 64) {                     // dir1: shape -> skel
        const int qb = x >> 5, ch = x & 31;
        pbase   = pw + ((size_t)b * 32 + ch) * 8192;
        q0      = qb * 4096 + tid;    // queries q0 + k*256, k<16
        qstride = 256;
        lbase   = 0;  scount = 64;
        ssrc    = skel + ((size_t)b * 2048 + ch * 64) * 3;
        q       = shape + (size_t)b * 8192 * 3;
    } else {                          // dir2: skel -> shape
        const int z = x - 64, half = tid >> 7;
        const int ch = 2 * z + half;
        pbase   = pw + P2_OFF + ((size_t)b * 128 + ch) * 2048;
        q0      = tid & 127;          // queries q0 + k*128, k<16
        qstride = 128;
        lbase   = half * 64;  scount = 128;
        ssrc    = shape + ((size_t)b * 8192 + z * 128) * 3;
        q       = skel + (size_t)b * 2048 * 3;
    }

    __shared__ float4 lds[128];

    // Stage targets as (x, y, z, |t|^2). dir1: 64, dir2: 128 (two chunks).
    if (tid < scount) {
        float tx = ssrc[tid * 3 + 0], ty = ssrc[tid * 3 + 1], tz = ssrc[tid * 3 + 2];
        lds[tid] = make_float4(tx, ty, tz, tx * tx + ty * ty + tz * tz);
    }

    // My QPT query points: precompute -2q and |q|^2.
    const float* qp = q + (size_t)q0 * 3;
    const int qs3 = qstride * 3;
    float nqx[QPT], nqy[QPT], nqz[QPT], qsq[QPT], mn[QPT];
    #pragma unroll
    for (int k = 0; k < QPT; ++k) {
        float xq = qp[k * qs3 + 0];
        float yq = qp[k * qs3 + 1];
        float zq = qp[k * qs3 + 2];
        nqx[k] = -2.0f * xq; nqy[k] = -2.0f * yq; nqz[k] = -2.0f * zq;
        qsq[k] = xq * xq + yq * yq + zq * zq;
        mn[k]  = BIGF;
    }

    __syncthreads();

    // Scan my 64 targets: per 2 targets & query -> 6 FMA + 1 v_min3_f32.
    // One broadcast ds_read_b128 feeds 16 queries.
    #pragma unroll 2
    for (int j = 0; j < 64; j += 2) {
        float4 ta = lds[lbase + j + 0];           // broadcast: conflict-free
        float4 tb = lds[lbase + j + 1];
        #pragma unroll
        for (int k = 0; k < QPT; ++k) {
            float e0 = fmaf(nqx[k], ta.x,
                       fmaf(nqy[k], ta.y,
                       fmaf(nqz[k], ta.z, ta.w)));
            float e1 = fmaf(nqx[k], tb.x,
                       fmaf(nqy[k], tb.y,
                       fmaf(nqz[k], tb.z, tb.w)));
            mn[k] = fminf(fminf(mn[k], e0), e1);  // v_min3_f32
        }
    }

    // One coalesced store per (query, chunk) partial — no atomics.
    #pragma unroll
    for (int k = 0; k < QPT; ++k)
        pbase[q0 + k * qstride] = qsq[k] + mn[k];
}

// 640 blocks: 64 queries/block, 4 lanes per query split over chunks.
// Blocks 0..511 = dir1 (32 chunks), 512..639 = dir2 (128 chunks).
__global__ __launch_bounds__(256) void reduce_kernel(
    const float* __restrict__ pw, float* __restrict__ psum)
{
    const int blk = blockIdx.x, tid = threadIdx.x;
    const int sub = tid & 3, qi = tid >> 2;       // 4 lanes per query

    float m = BIGF;
    if (blk < 512) {                              // dir1: 8 loads/lane
        const int b  = blk >> 7;
        const int ql = ((blk & 127) << 6) + qi;
        const float* p = pw + (size_t)b * 32 * 8192 + ql;
        #pragma unroll
        for (int i = 0; i < 8; ++i)
            m = fminf(m, p[(sub * 8 + i) * 8192]);
    } else {                                      // dir2: 32 loads/lane
        const int z  = blk - 512;
        const int b  = z >> 5;
        const int ql = ((z & 31) << 6) + qi;
        const float* p = pw + P2_OFF + (size_t)b * 128 * 2048 + ql;
        #pragma unroll
        for (int i = 0; i < 32; ++i)
            m = fminf(m, p[(sub * 32 + i) * 2048]);
    }

    // Min across the 4-lane group, clamp, keep one copy.
    m = fminf(m, __shfl_xor(m, 1));
    m = fminf(m, __shfl_xor(m, 2));
    float s = (sub == 0) ? fmaxf(m, 0.0f) : 0.0f;

    // Wave + block sum.
    #pragma unroll
    for (int off = 32; off > 0; off >>= 1)
        s += __shfl_down(s, off);

    __shared__ float wsum[4];
    const int lane = tid & 63, w = tid >> 6;
    if (lane == 0) wsum[w] = s;
    __syncthreads();
    if (tid == 0) psum[blk] = (wsum[0] + wsum[1]) + (wsum[2] + wsum[3]);
}

__global__ __launch_bounds__(256) void final_kernel(
    const float* __restrict__ psum, float* __restrict__ out)
{
    float s = psum[threadIdx.x] + psum[threadIdx.x + 256];
    if (threadIdx.x < 128) s += psum[threadIdx.x + 512];

    #pragma unroll
    for (int off = 32; off > 0; off >>= 1)
        s += __shfl_down(s, off);

    __shared__ float wsum[4];
    const int lane = threadIdx.x & 63, w = threadIdx.x >> 6;
    if (lane == 0) wsum[w] = s;
    __syncthreads();
    if (threadIdx.x == 0)
        out[0] = ((wsum[0] + wsum[1]) + (wsum[2] + wsum[3])) * 1.0e-4f;
}

extern "C" void kernel_launch(void* const* d_in, const int* in_sizes, int n_in,
                              void* d_out, int out_size, void* d_ws, size_t ws_size,
                              hipStream_t stream) {
    const float* shape = (const float*)d_in[0];   // [4, 8192, 3]
    const float* skel  = (const float*)d_in[1];   // [4, 2048, 3]
    float* out         = (float*)d_out;           // scalar f32
    float* pw          = (float*)d_ws;

    // 128 tiles/batch x 4 batches = 512 blocks (2/CU, 8 waves/CU).
    chamfer_kernel<<<dim3(128, 4), 256, 0, stream>>>(shape, skel, pw);

    // 640 blocks, then tiny deterministic final sum.
    reduce_kernel<<<RBLOCKS, 256, 0, stream>>>(pw, pw + PSUM_OFF);
    final_kernel<<<1, 256, 0, stream>>>(pw + PSUM_OFF, out);
}